// Round 5
// baseline (969.323 us; speedup 1.0000x reference)
//
#include <hip/hip_runtime.h>
#include <hip/hip_cooperative_groups.h>

namespace cg = cooperative_groups;

#define BB 8
#define TT 128
#define EE 256
#define VV 8192
#define LL 5
#define NROWS (BB*TT)   // 1024

typedef __attribute__((ext_vector_type(8))) short bf16x8;
typedef __attribute__((ext_vector_type(4))) float f32x4;

__device__ inline ushort f2bf(float f) {
    union { float f; unsigned u; } c; c.f = f;
    unsigned u = c.u;
    return (ushort)((u + 0x7FFF + ((u >> 16) & 1)) >> 16);  // RNE
}

// ================= mega kernel: prep + 5 transformer layers (cooperative) =================
// grid 256 x 256 threads, 64KB static LDS reused across phases.
__global__ __launch_bounds__(256) void mega_kernel(
        const int* __restrict__ idxs, const float* __restrict__ emb, const float* __restrict__ pos,
        const float* __restrict__ Wq, const float* __restrict__ Wk,
        const float* __restrict__ Wv, const float* __restrict__ Wfc,
        const float* __restrict__ Wlm, const float* __restrict__ bfc,
        float* __restrict__ xa, float* __restrict__ xb,
        float* __restrict__ qt, float* __restrict__ kt, float* __restrict__ vt,
        ushort* __restrict__ WTs, ushort* __restrict__ WlmT, float* __restrict__ loss_cell) {
    __shared__ ushort As[64*256];   // 32KB
    __shared__ ushort Bs[64*256];   // 32KB
    cg::grid_group grid = cg::this_grid();
    int tid = threadIdx.x, lane = tid & 63, w = tid >> 6;
    int blk = blockIdx.x;

    // ---------- phase 0: prep (1089 jobs) ----------
    for (int id = blk; id < 1089; id += 256) {
        if (id == 0) {
            if (tid == 0) *loss_cell = 0.f;
        } else if (id < 513) {
            ushort (*ts)[72] = (ushort(*)[72])As;
            int idw = id - 1;
            int v0 = (idw & 127) * 64, k0 = (idw >> 7) * 64;
            for (int kk = w; kk < 64; kk += 4)
                ts[lane][kk] = f2bf(Wlm[(size_t)(k0 + kk)*VV + v0 + lane]);
            __syncthreads();
            for (int vv = w; vv < 64; vv += 4)
                WlmT[(size_t)(v0 + vv)*EE + k0 + lane] = ts[vv][lane];
            __syncthreads();
        } else if (id < 833) {
            ushort (*ts)[72] = (ushort(*)[72])As;
            int idm = id - 513;
            int mat = idm >> 4, tile = idm & 15;
            int l = mat >> 2, type = mat & 3;
            const float* src = (type == 0 ? Wq : type == 1 ? Wk : type == 2 ? Wv : Wfc) + l*EE*EE;
            ushort* dst = WTs + mat*EE*EE;
            int i0 = (tile >> 2) * 64, o0 = (tile & 3) * 64;
            for (int ii = w; ii < 64; ii += 4)
                ts[lane][ii] = f2bf(src[(i0 + ii)*EE + o0 + lane]);
            __syncthreads();
            for (int oo = w; oo < 64; oo += 4)
                dst[(o0 + oo)*EE + i0 + lane] = ts[oo][lane];
            __syncthreads();
        } else {
            int row0 = (id - 833) * 4;
            for (int r = 0; r < 4; ++r) {
                int row = row0 + r;
                xa[row*EE + tid] = emb[(size_t)idxs[row]*EE + tid] + pos[(row & (TT-1))*EE + tid];
            }
        }
    }
    grid.sync();

    // ---------- 5 layers ----------
    for (int l = 0; l < LL; ++l) {
        float* xi = (l & 1) ? xb : xa;
        float* xo = (l & 1) ? xa : xb;
        const ushort* WTl = WTs + (size_t)l*4*EE*EE;

        // ----- qkv: 192 jobs (12 col/mat-tiles x 16 row-tiles) -----
        if (blk < 192) {
            int bx = blk % 12, by = blk / 12;
            int mat = bx >> 2;
            int c0 = (bx & 3) * 64;
            int r0 = by * 64;
            const ushort* WT = WTl + (size_t)mat*EE*EE;
            float* o = mat == 0 ? qt : (mat == 1 ? kt : vt);

            for (int rr = w; rr < 64; rr += 4) {
                float4 v = *(const float4*)&xi[(size_t)(r0 + rr)*EE + lane*4];
                ushort4 hh; hh.x = f2bf(v.x); hh.y = f2bf(v.y); hh.z = f2bf(v.z); hh.w = f2bf(v.w);
                *(ushort4*)&As[rr*256 + ((lane*4) ^ ((rr & 7) << 3))] = hh;
            }
            for (int it = 0; it < 8; ++it) {
                int c = w*16 + (lane >> 5) + 2*it;
                int k0i = (lane & 31) * 8;
                uint4 v = *(const uint4*)&WT[(size_t)(c0 + c)*EE + k0i];
                *(uint4*)&Bs[c*256 + (k0i ^ ((c & 7) << 3))] = v;
            }
            __syncthreads();
            f32x4 acc[4] = {};
            int rband = w*16 + (lane & 15);
            int kq = (lane >> 4) * 8;
            for (int ks = 0; ks < 8; ++ks) {
                int kk = ks*32 + kq;
                bf16x8 a = *(const bf16x8*)&As[rband*256 + (kk ^ ((rband & 7) << 3))];
                #pragma unroll
                for (int n = 0; n < 4; ++n) {
                    int c = n*16 + (lane & 15);
                    bf16x8 b = *(const bf16x8*)&Bs[c*256 + (kk ^ ((c & 7) << 3))];
                    acc[n] = __builtin_amdgcn_mfma_f32_16x16x32_bf16(a, b, acc[n], 0, 0, 0);
                }
            }
            int grow0 = r0 + w*16 + ((lane >> 4) << 2);
            int b = grow0 >> 7, t0 = grow0 & (TT-1);
            #pragma unroll
            for (int n = 0; n < 4; ++n) {
                int h = c0 + n*16 + (lane & 15);
                float4 vv = make_float4(acc[n][0], acc[n][1], acc[n][2], acc[n][3]);
                *(float4*)&o[((size_t)(b*EE + h))*TT + t0] = vv;
            }
            __syncthreads();
        }
        grid.sync();

        // ----- attn: 1024 jobs, 2 heads per job -----
        {
            float* fs = (float*)As;      // overlay: 5 arrays of [2][128]
            float* qs  = fs;
            float* ks_ = fs + 256;
            float* vs  = fs + 512;
            float* ms  = fs + 768;
            float* rzs = fs + 1024;
            int pair = tid >> 7;
            int t = tid & (TT-1);
            for (int job = blk; job < 1024; job += 256) {
                int bh = job*2 + pair;
                int b = bh >> 8, h = bh & 255;
                int base = bh * TT;
                qs[pair*TT + t]  = qt[base + t];
                ks_[pair*TT + t] = kt[base + t];
                vs[pair*TT + t]  = vt[base + t];
                __syncthreads();
                float k = ks_[pair*TT + t];
                float m = -INFINITY;
                for (int i = t; i < TT; ++i) m = fmaxf(m, qs[pair*TT + i] * k);
                float z = 0.f;
                for (int i = t; i < TT; ++i) z += __expf(qs[pair*TT + i] * k - m);
                ms[pair*TT + t] = m; rzs[pair*TT + t] = 1.f / z;
                __syncthreads();
                float q = qs[pair*TT + t];
                float acc = 0.f;
                for (int j = 0; j <= t; ++j)
                    acc += __expf(q * ks_[pair*TT + j] - ms[pair*TT + j]) * rzs[pair*TT + j] * vs[pair*TT + j];
                xi[(size_t)(b*TT + t)*EE + h] += acc;
                __syncthreads();
            }
        }
        grid.sync();

        // ----- fc: 64 jobs (4 col-tiles x 16 row-tiles) -----
        if (blk < 64) {
            const ushort* WT = WTl + (size_t)3*EE*EE;
            int c0 = (blk & 3) * 64;
            int r0 = (blk >> 2) * 64;
            for (int rr = w; rr < 64; rr += 4) {
                float4 v = *(const float4*)&xi[(size_t)(r0 + rr)*EE + lane*4];
                ushort4 hh; hh.x = f2bf(v.x); hh.y = f2bf(v.y); hh.z = f2bf(v.z); hh.w = f2bf(v.w);
                *(ushort4*)&As[rr*256 + ((lane*4) ^ ((rr & 7) << 3))] = hh;
            }
            for (int it = 0; it < 8; ++it) {
                int c = w*16 + (lane >> 5) + 2*it;
                int k0i = (lane & 31) * 8;
                uint4 v = *(const uint4*)&WT[(size_t)(c0 + c)*EE + k0i];
                *(uint4*)&Bs[c*256 + (k0i ^ ((c & 7) << 3))] = v;
            }
            __syncthreads();
            f32x4 acc[4] = {};
            int rband = w*16 + (lane & 15);
            int kq = (lane >> 4) * 8;
            for (int ks = 0; ks < 8; ++ks) {
                int kk = ks*32 + kq;
                bf16x8 a = *(const bf16x8*)&As[rband*256 + (kk ^ ((rband & 7) << 3))];
                #pragma unroll
                for (int n = 0; n < 4; ++n) {
                    int c = n*16 + (lane & 15);
                    bf16x8 b = *(const bf16x8*)&Bs[c*256 + (kk ^ ((c & 7) << 3))];
                    acc[n] = __builtin_amdgcn_mfma_f32_16x16x32_bf16(a, b, acc[n], 0, 0, 0);
                }
            }
            int grow0 = r0 + w*16 + ((lane >> 4) << 2);
            #pragma unroll
            for (int n = 0; n < 4; ++n) {
                int col = c0 + n*16 + (lane & 15);
                float bias = bfc[l*EE + col];
                #pragma unroll
                for (int j = 0; j < 4; ++j) {
                    size_t idx = (size_t)(grow0 + j)*EE + col;
                    xo[idx] = xi[idx] + fmaxf(acc[n][j] + bias, 0.f);
                }
            }
            __syncthreads();
        }
        if (l < LL-1) grid.sync();
    }
}

// ---------------- logits = x @ Wlm + blm (MFMA) + fused per-(row,64col) softmax partials
__global__ __launch_bounds__(256) void lm_mfma_kernel(
        const float* __restrict__ x, const ushort* __restrict__ WlmT,
        const float* __restrict__ blm, float* __restrict__ out,
        float* __restrict__ pm, float* __restrict__ pz) {
    __shared__ ushort As[64*256];
    __shared__ ushort Bs[64*256];
    int tid = threadIdx.x;
    int lane = tid & 63, w = tid >> 6;
    int c0 = blockIdx.x * 64;
    int r0 = blockIdx.y * 64;

    for (int rr = w; rr < 64; rr += 4) {
        float4 v = *(const float4*)&x[(size_t)(r0 + rr)*EE + lane*4];
        ushort4 hh; hh.x = f2bf(v.x); hh.y = f2bf(v.y); hh.z = f2bf(v.z); hh.w = f2bf(v.w);
        *(ushort4*)&As[rr*256 + ((lane*4) ^ ((rr & 7) << 3))] = hh;
    }
    for (int it = 0; it < 8; ++it) {
        int c = w*16 + (lane >> 5) + 2*it;
        int k0i = (lane & 31) * 8;
        uint4 v = *(const uint4*)&WlmT[(size_t)(c0 + c)*EE + k0i];
        *(uint4*)&Bs[c*256 + (k0i ^ ((c & 7) << 3))] = v;
    }
    __syncthreads();

    f32x4 acc[4] = {};
    int rband = w*16 + (lane & 15);
    int kq = (lane >> 4) * 8;
    for (int ks = 0; ks < 8; ++ks) {
        int kk = ks*32 + kq;
        bf16x8 a = *(const bf16x8*)&As[rband*256 + (kk ^ ((rband & 7) << 3))];
        #pragma unroll
        for (int n = 0; n < 4; ++n) {
            int c = n*16 + (lane & 15);
            bf16x8 b = *(const bf16x8*)&Bs[c*256 + (kk ^ ((c & 7) << 3))];
            acc[n] = __builtin_amdgcn_mfma_f32_16x16x32_bf16(a, b, acc[n], 0, 0, 0);
        }
    }

    float bias[4];
    #pragma unroll
    for (int n = 0; n < 4; ++n) bias[n] = blm[c0 + n*16 + (lane & 15)];
    int rowg = r0 + w*16 + (lane >> 4)*4;
    #pragma unroll
    for (int j = 0; j < 4; ++j) {
        float vals[4];
        float vmax = -INFINITY;
        #pragma unroll
        for (int n = 0; n < 4; ++n) {
            vals[n] = acc[n][j] + bias[n];
            out[(size_t)(rowg + j)*VV + c0 + n*16 + (lane & 15)] = vals[n];
            vmax = fmaxf(vmax, vals[n]);
        }
        #pragma unroll
        for (int m = 1; m <= 8; m <<= 1) vmax = fmaxf(vmax, __shfl_xor(vmax, m));
        float z = 0.f;
        #pragma unroll
        for (int n = 0; n < 4; ++n) z += __expf(vals[n] - vmax);
        #pragma unroll
        for (int m = 1; m <= 8; m <<= 1) z += __shfl_xor(z, m);
        if ((lane & 15) == 0) {
            pm[(size_t)(rowg + j)*128 + blockIdx.x] = vmax;
            pz[(size_t)(rowg + j)*128 + blockIdx.x] = z;
        }
    }
}

// ---------------- per-row loss from partials, atomicAdd mean into pre-zeroed loss cell
__global__ void loss_kernel(const float* __restrict__ pm, const float* __restrict__ pz,
                            const float* __restrict__ logits, const int* __restrict__ targets,
                            float* __restrict__ out_last) {
    int r = blockIdx.x;
    int t = threadIdx.x;             // 128
    __shared__ float sm[128], sz[128];
    float m = pm[(size_t)r*128 + t];
    float z = pz[(size_t)r*128 + t];
    sm[t] = m; __syncthreads();
    for (int s = 64; s > 0; s >>= 1) {
        if (t < s) sm[t] = fmaxf(sm[t], sm[t + s]);
        __syncthreads();
    }
    float M = sm[0];
    sz[t] = z * __expf(m - M); __syncthreads();
    for (int s = 64; s > 0; s >>= 1) {
        if (t < s) sz[t] += sz[t + s];
        __syncthreads();
    }
    if (t == 0) {
        float lse = M + logf(sz[0]);
        atomicAdd(out_last, (lse - logits[(size_t)r*VV + targets[r]]) * (1.0f / NROWS));
    }
}

extern "C" void kernel_launch(void* const* d_in, const int* in_sizes, int n_in,
                              void* d_out, int out_size, void* d_ws, size_t ws_size,
                              hipStream_t stream) {
    const int*   idxs    = (const int*)d_in[0];
    const int*   targets = (const int*)d_in[1];
    const float* emb     = (const float*)d_in[2];
    const float* pos     = (const float*)d_in[3];
    const float* Wq      = (const float*)d_in[4];
    const float* Wk      = (const float*)d_in[5];
    const float* Wv      = (const float*)d_in[6];
    const float* Wfc     = (const float*)d_in[7];
    const float* bfc     = (const float*)d_in[8];
    const float* Wlm     = (const float*)d_in[9];
    const float* blm     = (const float*)d_in[10];
    float* out = (float*)d_out;
    float* loss_cell = out + (size_t)NROWS * VV;

    float* ws = (float*)d_ws;
    float*  xa   = ws;                       // [1024,256]
    float*  xb   = xa + NROWS*EE;
    float*  qt   = xb + NROWS*EE;            // [B,H,T]
    float*  kt   = qt + NROWS*EE;
    float*  vt   = kt + NROWS*EE;
    float*  pm   = vt + NROWS*EE;            // [1024,128]
    float*  pz   = pm + NROWS*128;
    ushort* WTs  = (ushort*)(pz + NROWS*128);   // 20 * 256*256 bf16
    ushort* WlmT = WTs + 20*EE*EE;              // 8192*256 bf16

    void* kargs[] = {
        (void*)&idxs, (void*)&emb, (void*)&pos,
        (void*)&Wq, (void*)&Wk, (void*)&Wv, (void*)&Wfc,
        (void*)&Wlm, (void*)&bfc,
        (void*)&xa, (void*)&xb, (void*)&qt, (void*)&kt, (void*)&vt,
        (void*)&WTs, (void*)&WlmT, (void*)&loss_cell
    };
    hipLaunchCooperativeKernel((const void*)mega_kernel, dim3(256), dim3(256), kargs, 0, stream);

    lm_mfma_kernel<<<dim3(VV/64, NROWS/64), 256, 0, stream>>>(xb, WlmT, blm, out, pm, pz);
    loss_kernel<<<NROWS, 128, 0, stream>>>(pm, pz, out, targets, loss_cell);
}